// Round 1
// baseline (2277.814 us; speedup 1.0000x reference)
//
#include <hip/hip_runtime.h>
#include <math.h>

#define NN 100000
#define NE 1600000
#define FF 64
#define NB 64

// avg_deg['log'] = sum(log(i+1)*DEG[i]) / sum(DEG) = 196150.315/100100
__device__ __constant__ float AVG_LOG_F = 1.9595436f;

__device__ __forceinline__ unsigned f2mono(float x) {
    unsigned u = __float_as_uint(x);
    return (u >> 31) ? ~u : (u | 0x80000000u);
}
__device__ __forceinline__ float mono2f(unsigned u) {
    return __uint_as_float((u >> 31) ? (u & 0x7fffffffu) : ~u);
}
__device__ __forceinline__ void atomAddF(float* p, float v) {
    __hip_atomic_fetch_add(p, v, __ATOMIC_RELAXED, __HIP_MEMORY_SCOPE_AGENT);
}

// ---------------- fold weights: Wo'=Wo@Wl (stored transposed), We'=We@Wp2, biases ----------------
__global__ void fold_weights(const float* __restrict__ Wo, const float* __restrict__ Wl,
                             const float* __restrict__ bo, const float* __restrict__ bl,
                             const float* __restrict__ We, const float* __restrict__ Wp,
                             const float* __restrict__ bp, const float* __restrict__ be,
                             float* __restrict__ Wt,   // [64][832]  Wt[f][k] = (Wo@Wl)[k][f]
                             float* __restrict__ Wep,  // [16][64]
                             float* __restrict__ bpF, float* __restrict__ boF) {
    int t = blockIdx.x * blockDim.x + threadIdx.x;
    if (t < 832 * 64) {
        int k = t >> 6, f = t & 63;
        float acc = 0.f;
        for (int j = 0; j < 64; j++) acc += Wo[k * 64 + j] * Wl[j * 64 + f];
        Wt[f * 832 + k] = acc;
    } else if (t < 832 * 64 + 16 * 64) {
        int u = t - 832 * 64; int k = u >> 6, f = u & 63;
        float acc = 0.f;
        for (int j = 0; j < 64; j++) acc += We[k * 64 + j] * Wp[(128 + j) * 64 + f];
        Wep[k * 64 + f] = acc;
    } else if (t < 832 * 64 + 1024 + 64) {
        int f = t - (832 * 64 + 1024);
        float acc = bl[f];
        for (int j = 0; j < 64; j++) acc += bo[j] * Wl[j * 64 + f];
        boF[f] = acc;
    } else if (t < 832 * 64 + 1024 + 128) {
        int f = t - (832 * 64 + 1024 + 64);
        float acc = bp[f];
        for (int j = 0; j < 64; j++) acc += be[j] * Wp[(128 + j) * 64 + f];
        bpF[f] = acc;
    }
}

// ---------------- node pre-MLP + A/B projections (wave per node) ----------------
__global__ __launch_bounds__(256) void node_pre(const float* __restrict__ x,
                                                const float* __restrict__ W1, const float* __restrict__ b1,
                                                const float* __restrict__ W2, const float* __restrict__ b2,
                                                const float* __restrict__ Wp,
                                                float* __restrict__ x2, float* __restrict__ A, float* __restrict__ Bn) {
    __shared__ float W1s[64 * 32], W2s[32 * 64], Wp0s[64 * 64], Wp1s[64 * 64];
    __shared__ float xs[4][64], ts[4][32], x2s[4][64];
    int tid = threadIdx.x;
    for (int i = tid; i < 2048; i += 256) W1s[i] = W1[i];
    for (int i = tid; i < 2048; i += 256) W2s[i] = W2[i];
    for (int i = tid; i < 4096; i += 256) Wp0s[i] = Wp[i];
    for (int i = tid; i < 4096; i += 256) Wp1s[i] = Wp[4096 + i];
    __syncthreads();
    int w = tid >> 6, f = tid & 63;
    int wid = blockIdx.x * 4 + w;
    int nw = gridDim.x * 4;
    for (int v = wid; v < NN; v += nw) {
        xs[w][f] = x[(size_t)v * 64 + f];
        if (f < 32) {
            float tj = b1[f];
            for (int k = 0; k < 64; k++) tj += xs[w][k] * W1s[k * 32 + f];
            ts[w][f] = fmaxf(tj, 0.f);
        }
        float acc2 = b2[f];
        for (int k = 0; k < 32; k++) acc2 += ts[w][k] * W2s[k * 64 + f];
        x2s[w][f] = acc2;
        x2[(size_t)v * 64 + f] = acc2;
        float aa = 0.f, bb = 0.f;
        for (int k = 0; k < 64; k++) {
            float xv = x2s[w][k];
            aa += xv * Wp0s[k * 64 + f];
            bb += xv * Wp1s[k * 64 + f];
        }
        A[(size_t)v * 64 + f] = aa;
        Bn[(size_t)v * 64 + f] = bb;
    }
}

// ---------------- edge messages + multi-agg scatter (wave per edge) ----------------
__global__ __launch_bounds__(256) void edge_kernel(const float* __restrict__ ea, const int* __restrict__ ei,
                                                   const float* __restrict__ A, const float* __restrict__ Bn,
                                                   const float* __restrict__ Wep, const float* __restrict__ bpF,
                                                   float* __restrict__ sum, float* __restrict__ sum2,
                                                   unsigned* __restrict__ mnU, unsigned* __restrict__ mxU,
                                                   float* __restrict__ cnt) {
    __shared__ float Ws[16 * 64];
    __shared__ float bps[64];
    int tid = threadIdx.x;
    for (int i = tid; i < 1024; i += 256) Ws[i] = Wep[i];
    if (tid < 64) bps[tid] = bpF[tid];
    __syncthreads();
    int w = tid >> 6, f = tid & 63;
    int wid = blockIdx.x * 4 + w;
    int nw = gridDim.x * 4;
    for (int e = wid; e < NE; e += nw) {
        int src = ei[e];
        int dst = ei[NE + e];
        float eav = ea[(size_t)e * 16 + (f & 15)];
        float h = bps[f];
        #pragma unroll
        for (int k = 0; k < 16; k++) h += __shfl(eav, k, 64) * Ws[k * 64 + f];
        h += A[(size_t)dst * 64 + f] + Bn[(size_t)src * 64 + f];
        size_t o = (size_t)dst * 64 + f;
        atomAddF(&sum[o], h);
        atomAddF(&sum2[o], h * h);
        unsigned hu = f2mono(h);
        atomicMin(&mnU[o], hu);
        atomicMax(&mxU[o], hu);
        if (f == 0) atomAddF(&cnt[dst], 1.0f);
    }
}

// ---------------- post GEMM: out_pre = c[832] @ Wo' + bo', fused BN-stats ----------------
// block: 256 threads, 16 nodes; wave w computes feature f for nodes {w, w+4, w+8, w+12}
__global__ __launch_bounds__(256) void post_kernel(const float* __restrict__ x2,
                                                   const float* __restrict__ sum, const float* __restrict__ sum2,
                                                   const unsigned* __restrict__ mnU, const unsigned* __restrict__ mxU,
                                                   const float* __restrict__ cnt,
                                                   const float* __restrict__ Wt, const float* __restrict__ boF,
                                                   float* __restrict__ out_pre,
                                                   float* __restrict__ bnsum, float* __restrict__ bnsum2) {
    __shared__ float cs[16][840];    // 832 used, padded to 840 for 16B alignment
    __shared__ float bred[256];
    int tid = threadIdx.x, w = tid >> 6, f = tid & 63;
    int base = blockIdx.x * 16;      // 100000/16 = 6250 blocks exactly

    // phase A: build scaled feature vectors
    for (int g = 0; g < 4; ++g) {
        int n = g * 4 + w;
        int v = base + n;
        size_t o = (size_t)v * 64 + f;
        float c = cnt[v];
        float d = fmaxf(c, 1.f);
        float inv_d = 1.f / d;
        float mean = sum[o] * inv_d;
        float mean2 = sum2[o] * inv_d;
        float sd = sqrtf(fmaxf(mean2 - mean * mean, 0.f) + 1e-5f);
        bool has = c > 0.f;
        float mn = has ? mono2f(mnU[o]) : 0.f;
        float mx = has ? mono2f(mxU[o]) : 0.f;
        float amp = logf(d + 1.f) / AVG_LOG_F;
        float iamp = 1.f / amp;
        cs[n][f] = x2[o];
        cs[n][64 + f] = mean;        cs[n][128 + f] = mn;        cs[n][192 + f] = mx;        cs[n][256 + f] = sd;
        cs[n][320 + f] = mean * amp; cs[n][384 + f] = mn * amp;  cs[n][448 + f] = mx * amp;  cs[n][512 + f] = sd * amp;
        cs[n][576 + f] = mean * iamp; cs[n][640 + f] = mn * iamp; cs[n][704 + f] = mx * iamp; cs[n][768 + f] = sd * iamp;
    }
    __syncthreads();

    // phase B: 4 nodes per wave, k-loop over 832 with float4
    float acc0 = 0.f, acc1 = 0.f, acc2 = 0.f, acc3 = 0.f;
    const float* wrow = Wt + f * 832;
    for (int k = 0; k < 832; k += 4) {
        float4 wv = *(const float4*)(wrow + k);
        float4 c0 = *(const float4*)(&cs[w][k]);
        float4 c1 = *(const float4*)(&cs[w + 4][k]);
        float4 c2 = *(const float4*)(&cs[w + 8][k]);
        float4 c3 = *(const float4*)(&cs[w + 12][k]);
        acc0 += c0.x * wv.x + c0.y * wv.y + c0.z * wv.z + c0.w * wv.w;
        acc1 += c1.x * wv.x + c1.y * wv.y + c1.z * wv.z + c1.w * wv.w;
        acc2 += c2.x * wv.x + c2.y * wv.y + c2.z * wv.z + c2.w * wv.w;
        acc3 += c3.x * wv.x + c3.y * wv.y + c3.z * wv.z + c3.w * wv.w;
    }
    float bof = boF[f];
    float v0 = acc0 + bof, v1 = acc1 + bof, v2 = acc2 + bof, v3 = acc3 + bof;
    out_pre[(size_t)(base + w) * 64 + f] = v0;
    out_pre[(size_t)(base + w + 4) * 64 + f] = v1;
    out_pre[(size_t)(base + w + 8) * 64 + f] = v2;
    out_pre[(size_t)(base + w + 12) * 64 + f] = v3;

    // fused BN statistics (block partial -> atomic)
    float p1 = v0 + v1 + v2 + v3;
    float p2 = v0 * v0 + v1 * v1 + v2 * v2 + v3 * v3;
    __syncthreads();
    bred[tid] = p1;
    __syncthreads();
    float s1 = 0.f;
    if (tid < 64) s1 = bred[f] + bred[f + 64] + bred[f + 128] + bred[f + 192];
    __syncthreads();
    bred[tid] = p2;
    __syncthreads();
    if (tid < 64) {
        atomAddF(&bnsum[f], s1);
        atomAddF(&bnsum2[f], bred[f] + bred[f + 64] + bred[f + 128] + bred[f + 192]);
    }
}

// ---------------- BN finalize ----------------
__global__ void bn_finalize(const float* __restrict__ bnsum, const float* __restrict__ bnsum2,
                            const float* __restrict__ gamma, const float* __restrict__ beta,
                            float* __restrict__ bnscale, float* __restrict__ bnshift) {
    int f = threadIdx.x;
    if (f < 64) {
        float mu = bnsum[f] * (1.0f / NN);
        float var = bnsum2[f] * (1.0f / NN) - mu * mu;
        float sc = gamma[f] / sqrtf(var + 1e-5f);
        bnscale[f] = sc;
        bnshift[f] = beta[f] - mu * sc;
    }
}

// ---------------- BN apply + ReLU + global_add_pool ----------------
__global__ __launch_bounds__(256) void bn_pool(const float* __restrict__ out_pre, const int* __restrict__ batch,
                                               const float* __restrict__ bnscale, const float* __restrict__ bnshift,
                                               float* __restrict__ pooled) {
    __shared__ float red[256];
    int tid = threadIdx.x, f = tid & 63, q = tid >> 6;
    int base = blockIdx.x * 64;
    float sc = bnscale[f], sh = bnshift[f];
    int b_first = batch[base < NN ? base : NN - 1];
    int last = base + 63; if (last >= NN) last = NN - 1;
    int b_last = batch[last];
    if (b_first == b_last) {
        float local = 0.f;
        for (int g = 0; g < 16; ++g) {
            int v = base + g * 4 + q;
            if (v < NN) local += fmaxf(out_pre[(size_t)v * 64 + f] * sc + sh, 0.f);
        }
        red[tid] = local;
        __syncthreads();
        if (tid < 64) atomAddF(&pooled[b_first * 64 + f], red[f] + red[f + 64] + red[f + 128] + red[f + 192]);
    } else {
        for (int g = 0; g < 16; ++g) {
            int v = base + g * 4 + q;
            if (v < NN) {
                float val = fmaxf(out_pre[(size_t)v * 64 + f] * sc + sh, 0.f);
                atomAddF(&pooled[batch[v] * 64 + f], val);
            }
        }
    }
}

// ---------------- head MLP: relu(pooled@Wm1+bm1)@Wm2+bm2 ----------------
__global__ void head_kernel(const float* __restrict__ pooled,
                            const float* __restrict__ Wm1, const float* __restrict__ bm1,
                            const float* __restrict__ Wm2, const float* __restrict__ bm2,
                            float* __restrict__ out) {
    __shared__ float ts[64][104];
    int tid = threadIdx.x;
    for (int t = tid; t < 64 * 100; t += 256) {
        int b = t / 100, j = t % 100;
        float acc = bm1[j];
        for (int k = 0; k < 64; k++) acc += pooled[b * 64 + k] * Wm1[k * 100 + j];
        ts[b][j] = fmaxf(acc, 0.f);
    }
    __syncthreads();
    if (tid < 64) {
        float acc = bm2[0];
        for (int j = 0; j < 100; j++) acc += ts[tid][j] * Wm2[j];
        out[tid] = acc;
    }
}

extern "C" void kernel_launch(void* const* d_in, const int* in_sizes, int n_in,
                              void* d_out, int out_size, void* d_ws, size_t ws_size,
                              hipStream_t stream) {
    const float* x    = (const float*)d_in[0];
    const float* ea   = (const float*)d_in[1];
    const int*   ei   = (const int*)d_in[2];
    const int*   batch= (const int*)d_in[3];
    const float* W1   = (const float*)d_in[4];
    const float* b1   = (const float*)d_in[5];
    const float* W2   = (const float*)d_in[6];
    const float* b2   = (const float*)d_in[7];
    const float* We   = (const float*)d_in[8];
    const float* be   = (const float*)d_in[9];
    const float* Wp   = (const float*)d_in[10];
    const float* bp   = (const float*)d_in[11];
    const float* Wo   = (const float*)d_in[12];
    const float* bo   = (const float*)d_in[13];
    const float* Wl   = (const float*)d_in[14];
    const float* bl   = (const float*)d_in[15];
    const float* gamma= (const float*)d_in[16];
    const float* beta = (const float*)d_in[17];
    const float* Wm1  = (const float*)d_in[18];
    const float* bm1  = (const float*)d_in[19];
    const float* Wm2  = (const float*)d_in[20];
    const float* bm2  = (const float*)d_in[21];

    float* ws = (float*)d_ws;
    constexpr size_t NF = (size_t)NN * 64;              // 6,400,000
    const size_t o_x2     = 0;
    const size_t o_B      = NF;
    const size_t o_A      = 2 * NF;                     // aliased as out_pre after edge_kernel
    const size_t o_sum    = 3 * NF;                     // zero block start
    const size_t o_sum2   = 4 * NF;
    const size_t o_maxU   = 5 * NF;
    const size_t o_cnt    = 6 * NF;
    const size_t o_bnsum  = o_cnt + NN;
    const size_t o_bnsum2 = o_bnsum + 64;
    const size_t o_pooled = o_bnsum2 + 64;
    const size_t o_zend   = o_pooled + 64 * 64;         // zero block end
    const size_t o_mnU    = ((o_zend + 63) / 64) * 64;
    const size_t o_Wt     = o_mnU + NF;
    const size_t o_Wep    = o_Wt + 64 * 832;
    const size_t o_bpF    = o_Wep + 16 * 64;
    const size_t o_boF    = o_bpF + 64;
    const size_t o_bnscale= o_boF + 64;
    const size_t o_bnshift= o_bnscale + 64;

    hipMemsetAsync(ws + o_sum, 0, (o_zend - o_sum) * sizeof(float), stream);
    hipMemsetAsync(ws + o_mnU, 0xFF, NF * sizeof(float), stream);

    fold_weights<<<213, 256, 0, stream>>>(Wo, Wl, bo, bl, We, Wp, bp, be,
                                          ws + o_Wt, ws + o_Wep, ws + o_bpF, ws + o_boF);
    node_pre<<<1024, 256, 0, stream>>>(x, W1, b1, W2, b2, Wp,
                                       ws + o_x2, ws + o_A, ws + o_B);
    edge_kernel<<<4096, 256, 0, stream>>>(ea, ei, ws + o_A, ws + o_B,
                                          ws + o_Wep, ws + o_bpF,
                                          ws + o_sum, ws + o_sum2,
                                          (unsigned*)(ws + o_mnU), (unsigned*)(ws + o_maxU),
                                          ws + o_cnt);
    post_kernel<<<6250, 256, 0, stream>>>(ws + o_x2, ws + o_sum, ws + o_sum2,
                                          (const unsigned*)(ws + o_mnU), (const unsigned*)(ws + o_maxU),
                                          ws + o_cnt, ws + o_Wt, ws + o_boF,
                                          ws + o_A /*out_pre*/, ws + o_bnsum, ws + o_bnsum2);
    bn_finalize<<<1, 64, 0, stream>>>(ws + o_bnsum, ws + o_bnsum2, gamma, beta,
                                      ws + o_bnscale, ws + o_bnshift);
    bn_pool<<<1563, 256, 0, stream>>>(ws + o_A /*out_pre*/, batch,
                                      ws + o_bnscale, ws + o_bnshift, ws + o_pooled);
    head_kernel<<<1, 256, 0, stream>>>(ws + o_pooled, Wm1, bm1, Wm2, bm2, (float*)d_out);
}

// Round 2
// 1578.740 us; speedup vs baseline: 1.4428x; 1.4428x over previous
//
#include <hip/hip_runtime.h>
#include <math.h>

#define NN 100000
#define NE 1600000
#define FF 64
#define NB 64
#define NSCAN_BLOCKS 391   // ceil(NN/256)

// avg_deg['log'] = sum(log(i+1)*DEG[i]) / sum(DEG)
__device__ __constant__ float AVG_LOG_F = 1.9595436f;

__device__ __forceinline__ void atomAddF(float* p, float v) {
    __hip_atomic_fetch_add(p, v, __ATOMIC_RELAXED, __HIP_MEMORY_SCOPE_AGENT);
}

// ---------------- fold weights: Wo'=Wo@Wl (stored transposed), We'=We@Wp2, biases ----------------
__global__ void fold_weights(const float* __restrict__ Wo, const float* __restrict__ Wl,
                             const float* __restrict__ bo, const float* __restrict__ bl,
                             const float* __restrict__ We, const float* __restrict__ Wp,
                             const float* __restrict__ bp, const float* __restrict__ be,
                             float* __restrict__ Wt,   // [64][832]  Wt[f][k] = (Wo@Wl)[k][f]
                             float* __restrict__ Wep,  // [16][64]
                             float* __restrict__ bpF, float* __restrict__ boF) {
    int t = blockIdx.x * blockDim.x + threadIdx.x;
    if (t < 832 * 64) {
        int k = t >> 6, f = t & 63;
        float acc = 0.f;
        for (int j = 0; j < 64; j++) acc += Wo[k * 64 + j] * Wl[j * 64 + f];
        Wt[f * 832 + k] = acc;
    } else if (t < 832 * 64 + 16 * 64) {
        int u = t - 832 * 64; int k = u >> 6, f = u & 63;
        float acc = 0.f;
        for (int j = 0; j < 64; j++) acc += We[k * 64 + j] * Wp[(128 + j) * 64 + f];
        Wep[k * 64 + f] = acc;
    } else if (t < 832 * 64 + 1024 + 64) {
        int f = t - (832 * 64 + 1024);
        float acc = bl[f];
        for (int j = 0; j < 64; j++) acc += bo[j] * Wl[j * 64 + f];
        boF[f] = acc;
    } else if (t < 832 * 64 + 1024 + 128) {
        int f = t - (832 * 64 + 1024 + 64);
        float acc = bp[f];
        for (int j = 0; j < 64; j++) acc += be[j] * Wp[(128 + j) * 64 + f];
        bpF[f] = acc;
    }
}

// ---------------- node pre-MLP + A/B projections (wave per node) ----------------
__global__ __launch_bounds__(256) void node_pre(const float* __restrict__ x,
                                                const float* __restrict__ W1, const float* __restrict__ b1,
                                                const float* __restrict__ W2, const float* __restrict__ b2,
                                                const float* __restrict__ Wp,
                                                float* __restrict__ x2, float* __restrict__ A, float* __restrict__ Bn) {
    __shared__ float W1s[64 * 32], W2s[32 * 64], Wp0s[64 * 64], Wp1s[64 * 64];
    __shared__ float xs[4][64], ts[4][32], x2s[4][64];
    int tid = threadIdx.x;
    for (int i = tid; i < 2048; i += 256) W1s[i] = W1[i];
    for (int i = tid; i < 2048; i += 256) W2s[i] = W2[i];
    for (int i = tid; i < 4096; i += 256) Wp0s[i] = Wp[i];
    for (int i = tid; i < 4096; i += 256) Wp1s[i] = Wp[4096 + i];
    __syncthreads();
    int w = tid >> 6, f = tid & 63;
    int wid = blockIdx.x * 4 + w;
    int nw = gridDim.x * 4;
    for (int v = wid; v < NN; v += nw) {
        xs[w][f] = x[(size_t)v * 64 + f];
        if (f < 32) {
            float tj = b1[f];
            for (int k = 0; k < 64; k++) tj += xs[w][k] * W1s[k * 32 + f];
            ts[w][f] = fmaxf(tj, 0.f);
        }
        float acc2 = b2[f];
        for (int k = 0; k < 32; k++) acc2 += ts[w][k] * W2s[k * 64 + f];
        x2s[w][f] = acc2;
        x2[(size_t)v * 64 + f] = acc2;
        float aa = 0.f, bb = 0.f;
        for (int k = 0; k < 64; k++) {
            float xv = x2s[w][k];
            aa += xv * Wp0s[k * 64 + f];
            bb += xv * Wp1s[k * 64 + f];
        }
        A[(size_t)v * 64 + f] = aa;
        Bn[(size_t)v * 64 + f] = bb;
    }
}

// ---------------- counting sort of edges by dst ----------------
__global__ void hist_kernel(const int* __restrict__ ei, unsigned* __restrict__ cnt_i) {
    int t = blockIdx.x * blockDim.x + threadIdx.x;
    if (t < NE) atomicAdd(&cnt_i[ei[NE + t]], 1u);
}

__global__ void scan_blocksum(const unsigned* __restrict__ cnt_i, unsigned* __restrict__ bsum) {
    __shared__ unsigned red[256];
    int t = blockIdx.x * 256 + threadIdx.x;
    unsigned c = (t < NN) ? cnt_i[t] : 0u;
    red[threadIdx.x] = c; __syncthreads();
    for (int s = 128; s > 0; s >>= 1) {
        if (threadIdx.x < s) red[threadIdx.x] += red[threadIdx.x + s];
        __syncthreads();
    }
    if (threadIdx.x == 0) bsum[blockIdx.x] = red[0];
}

__global__ void scan_top(const unsigned* __restrict__ bsum, unsigned* __restrict__ boff,
                         unsigned* __restrict__ start) {
    __shared__ unsigned sh[512];
    int t = threadIdx.x;
    unsigned v = (t < NSCAN_BLOCKS) ? bsum[t] : 0u;
    sh[t] = v; __syncthreads();
    for (int d = 1; d < 512; d <<= 1) {
        unsigned add = (t >= d) ? sh[t - d] : 0u;
        __syncthreads();
        sh[t] += add;
        __syncthreads();
    }
    if (t < NSCAN_BLOCKS) boff[t] = sh[t] - v;   // exclusive
    if (t == 0) start[NN] = NE;
}

__global__ void scan_final(const unsigned* __restrict__ cnt_i, const unsigned* __restrict__ boff,
                           unsigned* __restrict__ start) {
    __shared__ unsigned sh[256];
    int b = blockIdx.x, t = threadIdx.x;
    int v = b * 256 + t;
    unsigned c = (v < NN) ? cnt_i[v] : 0u;
    sh[t] = c; __syncthreads();
    for (int d = 1; d < 256; d <<= 1) {
        unsigned add = (t >= d) ? sh[t - d] : 0u;
        __syncthreads();
        sh[t] += add;
        __syncthreads();
    }
    if (v < NN) start[v] = boff[b] + sh[t] - c;  // exclusive scan
}

__global__ void scatter_kernel(const int* __restrict__ ei, const unsigned* __restrict__ start,
                               unsigned* __restrict__ cnt_i, unsigned* __restrict__ perm) {
    int t = blockIdx.x * blockDim.x + threadIdx.x;
    if (t < NE) {
        int d = ei[NE + t];
        unsigned old = atomicSub(&cnt_i[d], 1u);
        perm[start[d] + old - 1u] = (unsigned)t;
    }
}

// ---------------- per-node segment aggregation (wave per node, no atomics) ----------------
__global__ __launch_bounds__(256) void agg_kernel(const float* __restrict__ ea, const int* __restrict__ ei,
                                                  const unsigned* __restrict__ perm, const unsigned* __restrict__ start,
                                                  const float* __restrict__ A, const float* __restrict__ Bn,
                                                  const float* __restrict__ Wep, const float* __restrict__ bpF,
                                                  float* __restrict__ meanO, float* __restrict__ mnO,
                                                  float* __restrict__ mxO, float* __restrict__ sdO,
                                                  float* __restrict__ cntO) {
    int tid = threadIdx.x, w = tid >> 6, f = tid & 63;
    float wcol[16];
    #pragma unroll
    for (int k = 0; k < 16; k++) wcol[k] = Wep[k * 64 + f];
    float bpf = bpF[f];
    int wid = blockIdx.x * 4 + w;
    int nw = gridDim.x * 4;
    for (int v = wid; v < NN; v += nw) {
        unsigned s0 = start[v], s1 = start[v + 1];
        float av = A[(size_t)v * 64 + f] + bpf;
        float s = 0.f, s2 = 0.f, mn = INFINITY, mx = -INFINITY;
        for (unsigned j = s0; j < s1; ++j) {
            unsigned e = perm[j];
            int src = ei[e];
            const float4* ept = (const float4*)(ea + (size_t)e * 16);
            float4 e0 = ept[0], e1 = ept[1], e2 = ept[2], e3 = ept[3];
            float h = av + Bn[(size_t)src * 64 + f];
            h += e0.x * wcol[0] + e0.y * wcol[1] + e0.z * wcol[2] + e0.w * wcol[3];
            h += e1.x * wcol[4] + e1.y * wcol[5] + e1.z * wcol[6] + e1.w * wcol[7];
            h += e2.x * wcol[8] + e2.y * wcol[9] + e2.z * wcol[10] + e2.w * wcol[11];
            h += e3.x * wcol[12] + e3.y * wcol[13] + e3.z * wcol[14] + e3.w * wcol[15];
            s += h; s2 += h * h;
            mn = fminf(mn, h); mx = fmaxf(mx, h);
        }
        float c = (float)(s1 - s0);
        float d = fmaxf(c, 1.f);
        float inv = 1.f / d;
        float mean = s * inv, mean2 = s2 * inv;
        float sd = sqrtf(fmaxf(mean2 - mean * mean, 0.f) + 1e-5f);
        bool has = s1 > s0;
        size_t o = (size_t)v * 64 + f;
        meanO[o] = mean;
        mnO[o] = has ? mn : 0.f;
        mxO[o] = has ? mx : 0.f;
        sdO[o] = sd;
        if (f == 0) cntO[v] = c;
    }
}

// ---------------- post GEMM: out_pre = c[832] @ Wo' + bo', fused BN-stats ----------------
__global__ __launch_bounds__(256) void post_kernel(const float* __restrict__ x2,
                                                   const float* __restrict__ meanI, const float* __restrict__ mnI,
                                                   const float* __restrict__ mxI, const float* __restrict__ sdI,
                                                   const float* __restrict__ cnt,
                                                   const float* __restrict__ Wt, const float* __restrict__ boF,
                                                   float* __restrict__ out_pre,
                                                   float* __restrict__ bnsum, float* __restrict__ bnsum2) {
    __shared__ float cs[16][840];    // 832 used, padded to 840 for 16B alignment
    __shared__ float bred[256];
    int tid = threadIdx.x, w = tid >> 6, f = tid & 63;
    int base = blockIdx.x * 16;      // 100000/16 = 6250 blocks exactly

    // phase A: build scaled feature vectors
    for (int g = 0; g < 4; ++g) {
        int n = g * 4 + w;
        int v = base + n;
        size_t o = (size_t)v * 64 + f;
        float c = cnt[v];
        float d = fmaxf(c, 1.f);
        float mean = meanI[o];
        float sd = sdI[o];
        float mn = mnI[o];
        float mx = mxI[o];
        float amp = logf(d + 1.f) / AVG_LOG_F;
        float iamp = 1.f / amp;
        cs[n][f] = x2[o];
        cs[n][64 + f] = mean;        cs[n][128 + f] = mn;        cs[n][192 + f] = mx;        cs[n][256 + f] = sd;
        cs[n][320 + f] = mean * amp; cs[n][384 + f] = mn * amp;  cs[n][448 + f] = mx * amp;  cs[n][512 + f] = sd * amp;
        cs[n][576 + f] = mean * iamp; cs[n][640 + f] = mn * iamp; cs[n][704 + f] = mx * iamp; cs[n][768 + f] = sd * iamp;
    }
    __syncthreads();

    // phase B: 4 nodes per wave, k-loop over 832 with float4
    float acc0 = 0.f, acc1 = 0.f, acc2 = 0.f, acc3 = 0.f;
    const float* wrow = Wt + f * 832;
    for (int k = 0; k < 832; k += 4) {
        float4 wv = *(const float4*)(wrow + k);
        float4 c0 = *(const float4*)(&cs[w][k]);
        float4 c1 = *(const float4*)(&cs[w + 4][k]);
        float4 c2 = *(const float4*)(&cs[w + 8][k]);
        float4 c3 = *(const float4*)(&cs[w + 12][k]);
        acc0 += c0.x * wv.x + c0.y * wv.y + c0.z * wv.z + c0.w * wv.w;
        acc1 += c1.x * wv.x + c1.y * wv.y + c1.z * wv.z + c1.w * wv.w;
        acc2 += c2.x * wv.x + c2.y * wv.y + c2.z * wv.z + c2.w * wv.w;
        acc3 += c3.x * wv.x + c3.y * wv.y + c3.z * wv.z + c3.w * wv.w;
    }
    float bof = boF[f];
    float v0 = acc0 + bof, v1 = acc1 + bof, v2 = acc2 + bof, v3 = acc3 + bof;
    out_pre[(size_t)(base + w) * 64 + f] = v0;
    out_pre[(size_t)(base + w + 4) * 64 + f] = v1;
    out_pre[(size_t)(base + w + 8) * 64 + f] = v2;
    out_pre[(size_t)(base + w + 12) * 64 + f] = v3;

    // fused BN statistics (block partial -> atomic)
    float p1 = v0 + v1 + v2 + v3;
    float p2 = v0 * v0 + v1 * v1 + v2 * v2 + v3 * v3;
    __syncthreads();
    bred[tid] = p1;
    __syncthreads();
    float s1 = 0.f;
    if (tid < 64) s1 = bred[f] + bred[f + 64] + bred[f + 128] + bred[f + 192];
    __syncthreads();
    bred[tid] = p2;
    __syncthreads();
    if (tid < 64) {
        atomAddF(&bnsum[f], s1);
        atomAddF(&bnsum2[f], bred[f] + bred[f + 64] + bred[f + 128] + bred[f + 192]);
    }
}

// ---------------- BN finalize ----------------
__global__ void bn_finalize(const float* __restrict__ bnsum, const float* __restrict__ bnsum2,
                            const float* __restrict__ gamma, const float* __restrict__ beta,
                            float* __restrict__ bnscale, float* __restrict__ bnshift) {
    int f = threadIdx.x;
    if (f < 64) {
        float mu = bnsum[f] * (1.0f / NN);
        float var = bnsum2[f] * (1.0f / NN) - mu * mu;
        float sc = gamma[f] / sqrtf(var + 1e-5f);
        bnscale[f] = sc;
        bnshift[f] = beta[f] - mu * sc;
    }
}

// ---------------- BN apply + ReLU + global_add_pool ----------------
__global__ __launch_bounds__(256) void bn_pool(const float* __restrict__ out_pre, const int* __restrict__ batch,
                                               const float* __restrict__ bnscale, const float* __restrict__ bnshift,
                                               float* __restrict__ pooled) {
    __shared__ float red[256];
    int tid = threadIdx.x, f = tid & 63, q = tid >> 6;
    int base = blockIdx.x * 64;
    float sc = bnscale[f], sh = bnshift[f];
    int b_first = batch[base < NN ? base : NN - 1];
    int last = base + 63; if (last >= NN) last = NN - 1;
    int b_last = batch[last];
    if (b_first == b_last) {
        float local = 0.f;
        for (int g = 0; g < 16; ++g) {
            int v = base + g * 4 + q;
            if (v < NN) local += fmaxf(out_pre[(size_t)v * 64 + f] * sc + sh, 0.f);
        }
        red[tid] = local;
        __syncthreads();
        if (tid < 64) atomAddF(&pooled[b_first * 64 + f], red[f] + red[f + 64] + red[f + 128] + red[f + 192]);
    } else {
        for (int g = 0; g < 16; ++g) {
            int v = base + g * 4 + q;
            if (v < NN) {
                float val = fmaxf(out_pre[(size_t)v * 64 + f] * sc + sh, 0.f);
                atomAddF(&pooled[batch[v] * 64 + f], val);
            }
        }
    }
}

// ---------------- head MLP: relu(pooled@Wm1+bm1)@Wm2+bm2 ----------------
__global__ void head_kernel(const float* __restrict__ pooled,
                            const float* __restrict__ Wm1, const float* __restrict__ bm1,
                            const float* __restrict__ Wm2, const float* __restrict__ bm2,
                            float* __restrict__ out) {
    __shared__ float ts[64][104];
    int tid = threadIdx.x;
    for (int t = tid; t < 64 * 100; t += 256) {
        int b = t / 100, j = t % 100;
        float acc = bm1[j];
        for (int k = 0; k < 64; k++) acc += pooled[b * 64 + k] * Wm1[k * 100 + j];
        ts[b][j] = fmaxf(acc, 0.f);
    }
    __syncthreads();
    if (tid < 64) {
        float acc = bm2[0];
        for (int j = 0; j < 100; j++) acc += ts[tid][j] * Wm2[j];
        out[tid] = acc;
    }
}

extern "C" void kernel_launch(void* const* d_in, const int* in_sizes, int n_in,
                              void* d_out, int out_size, void* d_ws, size_t ws_size,
                              hipStream_t stream) {
    const float* x    = (const float*)d_in[0];
    const float* ea   = (const float*)d_in[1];
    const int*   ei   = (const int*)d_in[2];
    const int*   batch= (const int*)d_in[3];
    const float* W1   = (const float*)d_in[4];
    const float* b1   = (const float*)d_in[5];
    const float* W2   = (const float*)d_in[6];
    const float* b2   = (const float*)d_in[7];
    const float* We   = (const float*)d_in[8];
    const float* be   = (const float*)d_in[9];
    const float* Wp   = (const float*)d_in[10];
    const float* bp   = (const float*)d_in[11];
    const float* Wo   = (const float*)d_in[12];
    const float* bo   = (const float*)d_in[13];
    const float* Wl   = (const float*)d_in[14];
    const float* bl   = (const float*)d_in[15];
    const float* gamma= (const float*)d_in[16];
    const float* beta = (const float*)d_in[17];
    const float* Wm1  = (const float*)d_in[18];
    const float* bm1  = (const float*)d_in[19];
    const float* Wm2  = (const float*)d_in[20];
    const float* bm2  = (const float*)d_in[21];

    float* ws = (float*)d_ws;
    constexpr size_t NF = (size_t)NN * 64;              // 6,400,000
    const size_t o_x2     = 0;
    const size_t o_B      = NF;
    const size_t o_A      = 2 * NF;                     // reused as out_pre after agg_kernel
    const size_t o_mean   = 3 * NF;
    const size_t o_mn     = 4 * NF;
    const size_t o_mx     = 5 * NF;
    const size_t o_sd     = 6 * NF;
    const size_t o_cntf   = 7 * NF;
    const size_t o_start  = o_cntf + NN;                // NN+1 uints
    const size_t o_cnt_i  = o_start + NN + 2;           // NN uints (memset 0)
    const size_t o_bsum   = o_cnt_i + NN;
    const size_t o_boff   = o_bsum + 512;
    const size_t o_perm   = o_boff + 512;               // NE uints
    const size_t o_Wt     = o_perm + NE;
    const size_t o_Wep    = o_Wt + 64 * 832;
    const size_t o_bpF    = o_Wep + 16 * 64;
    const size_t o_boF    = o_bpF + 64;
    const size_t o_bnscale= o_boF + 64;
    const size_t o_bnshift= o_bnscale + 64;
    const size_t o_pooled = o_bnshift + 64;             // zero block: pooled + bnsum + bnsum2
    const size_t o_bnsum  = o_pooled + 64 * 64;
    const size_t o_bnsum2 = o_bnsum + 64;

    // zero the histogram and the small accumulators
    hipMemsetAsync(ws + o_cnt_i, 0, NN * sizeof(unsigned), stream);
    hipMemsetAsync(ws + o_pooled, 0, (64 * 64 + 128) * sizeof(float), stream);

    fold_weights<<<213, 256, 0, stream>>>(Wo, Wl, bo, bl, We, Wp, bp, be,
                                          ws + o_Wt, ws + o_Wep, ws + o_bpF, ws + o_boF);
    node_pre<<<1024, 256, 0, stream>>>(x, W1, b1, W2, b2, Wp,
                                       ws + o_x2, ws + o_A, ws + o_B);
    hist_kernel<<<6250, 256, 0, stream>>>(ei, (unsigned*)(ws + o_cnt_i));
    scan_blocksum<<<NSCAN_BLOCKS, 256, 0, stream>>>((unsigned*)(ws + o_cnt_i), (unsigned*)(ws + o_bsum));
    scan_top<<<1, 512, 0, stream>>>((unsigned*)(ws + o_bsum), (unsigned*)(ws + o_boff),
                                    (unsigned*)(ws + o_start));
    scan_final<<<NSCAN_BLOCKS, 256, 0, stream>>>((unsigned*)(ws + o_cnt_i), (unsigned*)(ws + o_boff),
                                                 (unsigned*)(ws + o_start));
    scatter_kernel<<<6250, 256, 0, stream>>>(ei, (const unsigned*)(ws + o_start),
                                             (unsigned*)(ws + o_cnt_i), (unsigned*)(ws + o_perm));
    agg_kernel<<<4096, 256, 0, stream>>>(ea, ei, (const unsigned*)(ws + o_perm),
                                         (const unsigned*)(ws + o_start),
                                         ws + o_A, ws + o_B, ws + o_Wep, ws + o_bpF,
                                         ws + o_mean, ws + o_mn, ws + o_mx, ws + o_sd, ws + o_cntf);
    post_kernel<<<6250, 256, 0, stream>>>(ws + o_x2, ws + o_mean, ws + o_mn, ws + o_mx, ws + o_sd,
                                          ws + o_cntf, ws + o_Wt, ws + o_boF,
                                          ws + o_A /*out_pre*/, ws + o_bnsum, ws + o_bnsum2);
    bn_finalize<<<1, 64, 0, stream>>>(ws + o_bnsum, ws + o_bnsum2, gamma, beta,
                                      ws + o_bnscale, ws + o_bnshift);
    bn_pool<<<1563, 256, 0, stream>>>(ws + o_A /*out_pre*/, batch,
                                      ws + o_bnscale, ws + o_bnshift, ws + o_pooled);
    head_kernel<<<1, 256, 0, stream>>>(ws + o_pooled, Wm1, bm1, Wm2, bm2, (float*)d_out);
}

// Round 3
// 1240.696 us; speedup vs baseline: 1.8359x; 1.2725x over previous
//
#include <hip/hip_runtime.h>
#include <hip/hip_bf16.h>
#include <math.h>

#define NN 100000
#define NE 1600000
#define FF 64
#define NB 64
#define NSCAN_BLOCKS 391   // ceil(NN/256)

// avg_deg['log'] = sum(log(i+1)*DEG[i]) / sum(DEG)
__device__ __constant__ float AVG_LOG_F = 1.9595436f;

typedef short short8 __attribute__((ext_vector_type(8)));
typedef float f32x4 __attribute__((ext_vector_type(4)));

__device__ __forceinline__ void atomAddF(float* p, float v) {
    __hip_atomic_fetch_add(p, v, __ATOMIC_RELAXED, __HIP_MEMORY_SCOPE_AGENT);
}

// ---------------- fold weights: Wtb = (Wo@Wl)^T in bf16, We'=We@Wp2, biases ----------------
__global__ void fold_weights(const float* __restrict__ Wo, const float* __restrict__ Wl,
                             const float* __restrict__ bo, const float* __restrict__ bl,
                             const float* __restrict__ We, const float* __restrict__ Wp,
                             const float* __restrict__ bp, const float* __restrict__ be,
                             __hip_bfloat16* __restrict__ Wtb,   // [64][832]  Wtb[f][k] = (Wo@Wl)[k][f]
                             float* __restrict__ Wep,  // [16][64]
                             float* __restrict__ bpF, float* __restrict__ boF) {
    int t = blockIdx.x * blockDim.x + threadIdx.x;
    if (t < 832 * 64) {
        int k = t >> 6, f = t & 63;
        float acc = 0.f;
        for (int j = 0; j < 64; j++) acc += Wo[k * 64 + j] * Wl[j * 64 + f];
        Wtb[f * 832 + k] = __float2bfloat16(acc);
    } else if (t < 832 * 64 + 16 * 64) {
        int u = t - 832 * 64; int k = u >> 6, f = u & 63;
        float acc = 0.f;
        for (int j = 0; j < 64; j++) acc += We[k * 64 + j] * Wp[(128 + j) * 64 + f];
        Wep[k * 64 + f] = acc;
    } else if (t < 832 * 64 + 1024 + 64) {
        int f = t - (832 * 64 + 1024);
        float acc = bl[f];
        for (int j = 0; j < 64; j++) acc += bo[j] * Wl[j * 64 + f];
        boF[f] = acc;
    } else if (t < 832 * 64 + 1024 + 128) {
        int f = t - (832 * 64 + 1024 + 64);
        float acc = bp[f];
        for (int j = 0; j < 64; j++) acc += be[j] * Wp[(128 + j) * 64 + f];
        bpF[f] = acc;
    }
}

// ---------------- node pre-MLP + A/B projections (wave per node) ----------------
__global__ __launch_bounds__(256) void node_pre(const float* __restrict__ x,
                                                const float* __restrict__ W1, const float* __restrict__ b1,
                                                const float* __restrict__ W2, const float* __restrict__ b2,
                                                const float* __restrict__ Wp,
                                                float* __restrict__ x2, float* __restrict__ A, float* __restrict__ Bn) {
    __shared__ float W1s[64 * 32], W2s[32 * 64], Wp0s[64 * 64], Wp1s[64 * 64];
    __shared__ float xs[4][64], ts[4][32], x2s[4][64];
    int tid = threadIdx.x;
    for (int i = tid; i < 2048; i += 256) W1s[i] = W1[i];
    for (int i = tid; i < 2048; i += 256) W2s[i] = W2[i];
    for (int i = tid; i < 4096; i += 256) Wp0s[i] = Wp[i];
    for (int i = tid; i < 4096; i += 256) Wp1s[i] = Wp[4096 + i];
    __syncthreads();
    int w = tid >> 6, f = tid & 63;
    int wid = blockIdx.x * 4 + w;
    int nw = gridDim.x * 4;
    for (int v = wid; v < NN; v += nw) {
        xs[w][f] = x[(size_t)v * 64 + f];
        if (f < 32) {
            float tj = b1[f];
            for (int k = 0; k < 64; k++) tj += xs[w][k] * W1s[k * 32 + f];
            ts[w][f] = fmaxf(tj, 0.f);
        }
        float acc2 = b2[f];
        for (int k = 0; k < 32; k++) acc2 += ts[w][k] * W2s[k * 64 + f];
        x2s[w][f] = acc2;
        x2[(size_t)v * 64 + f] = acc2;
        float aa = 0.f, bb = 0.f;
        for (int k = 0; k < 64; k++) {
            float xv = x2s[w][k];
            aa += xv * Wp0s[k * 64 + f];
            bb += xv * Wp1s[k * 64 + f];
        }
        A[(size_t)v * 64 + f] = aa;
        Bn[(size_t)v * 64 + f] = bb;
    }
}

// ---------------- counting sort of edges by dst ----------------
__global__ void hist_kernel(const int* __restrict__ ei, unsigned* __restrict__ cnt_i) {
    int t = blockIdx.x * blockDim.x + threadIdx.x;
    if (t < NE) atomicAdd(&cnt_i[ei[NE + t]], 1u);
}

__global__ void scan_blocksum(const unsigned* __restrict__ cnt_i, unsigned* __restrict__ bsum) {
    __shared__ unsigned red[256];
    int t = blockIdx.x * 256 + threadIdx.x;
    unsigned c = (t < NN) ? cnt_i[t] : 0u;
    red[threadIdx.x] = c; __syncthreads();
    for (int s = 128; s > 0; s >>= 1) {
        if (threadIdx.x < s) red[threadIdx.x] += red[threadIdx.x + s];
        __syncthreads();
    }
    if (threadIdx.x == 0) bsum[blockIdx.x] = red[0];
}

__global__ void scan_top(const unsigned* __restrict__ bsum, unsigned* __restrict__ boff,
                         unsigned* __restrict__ start) {
    __shared__ unsigned sh[512];
    int t = threadIdx.x;
    unsigned v = (t < NSCAN_BLOCKS) ? bsum[t] : 0u;
    sh[t] = v; __syncthreads();
    for (int d = 1; d < 512; d <<= 1) {
        unsigned add = (t >= d) ? sh[t - d] : 0u;
        __syncthreads();
        sh[t] += add;
        __syncthreads();
    }
    if (t < NSCAN_BLOCKS) boff[t] = sh[t] - v;   // exclusive
    if (t == 0) start[NN] = NE;
}

__global__ void scan_final(const unsigned* __restrict__ cnt_i, const unsigned* __restrict__ boff,
                           unsigned* __restrict__ start) {
    __shared__ unsigned sh[256];
    int b = blockIdx.x, t = threadIdx.x;
    int v = b * 256 + t;
    unsigned c = (v < NN) ? cnt_i[v] : 0u;
    sh[t] = c; __syncthreads();
    for (int d = 1; d < 256; d <<= 1) {
        unsigned add = (t >= d) ? sh[t - d] : 0u;
        __syncthreads();
        sh[t] += add;
        __syncthreads();
    }
    if (v < NN) start[v] = boff[b] + sh[t] - c;  // exclusive scan
}

__global__ void scatter_kernel(const int* __restrict__ ei, const unsigned* __restrict__ start,
                               unsigned* __restrict__ cnt_i, unsigned* __restrict__ perm) {
    int t = blockIdx.x * blockDim.x + threadIdx.x;
    if (t < NE) {
        int d = ei[NE + t];
        unsigned old = atomicSub(&cnt_i[d], 1u);
        perm[start[d] + old - 1u] = (unsigned)t;
    }
}

// ---------------- per-node segment aggregation (wave per node, no atomics) ----------------
__global__ __launch_bounds__(256) void agg_kernel(const float* __restrict__ ea, const int* __restrict__ ei,
                                                  const unsigned* __restrict__ perm, const unsigned* __restrict__ start,
                                                  const float* __restrict__ A, const float* __restrict__ Bn,
                                                  const float* __restrict__ Wep, const float* __restrict__ bpF,
                                                  float* __restrict__ meanO, float* __restrict__ mnO,
                                                  float* __restrict__ mxO, float* __restrict__ sdO,
                                                  float* __restrict__ cntO) {
    int tid = threadIdx.x, w = tid >> 6, f = tid & 63;
    float wcol[16];
    #pragma unroll
    for (int k = 0; k < 16; k++) wcol[k] = Wep[k * 64 + f];
    float bpf = bpF[f];
    int wid = blockIdx.x * 4 + w;
    int nw = gridDim.x * 4;
    for (int v = wid; v < NN; v += nw) {
        unsigned s0 = start[v], s1 = start[v + 1];
        float av = A[(size_t)v * 64 + f] + bpf;
        float s = 0.f, s2 = 0.f, mn = INFINITY, mx = -INFINITY;
        for (unsigned j = s0; j < s1; ++j) {
            unsigned e = perm[j];
            int src = ei[e];
            const float4* ept = (const float4*)(ea + (size_t)e * 16);
            float4 e0 = ept[0], e1 = ept[1], e2 = ept[2], e3 = ept[3];
            float h = av + Bn[(size_t)src * 64 + f];
            h += e0.x * wcol[0] + e0.y * wcol[1] + e0.z * wcol[2] + e0.w * wcol[3];
            h += e1.x * wcol[4] + e1.y * wcol[5] + e1.z * wcol[6] + e1.w * wcol[7];
            h += e2.x * wcol[8] + e2.y * wcol[9] + e2.z * wcol[10] + e2.w * wcol[11];
            h += e3.x * wcol[12] + e3.y * wcol[13] + e3.z * wcol[14] + e3.w * wcol[15];
            s += h; s2 += h * h;
            mn = fminf(mn, h); mx = fmaxf(mx, h);
        }
        float c = (float)(s1 - s0);
        float d = fmaxf(c, 1.f);
        float inv = 1.f / d;
        float mean = s * inv, mean2 = s2 * inv;
        float sd = sqrtf(fmaxf(mean2 - mean * mean, 0.f) + 1e-5f);
        bool has = s1 > s0;
        size_t o = (size_t)v * 64 + f;
        meanO[o] = mean;
        mnO[o] = has ? mn : 0.f;
        mxO[o] = has ? mx : 0.f;
        sdO[o] = sd;
        if (f == 0) cntO[v] = c;
    }
}

// ---------------- post GEMM via MFMA: out_pre = cs[832] @ (Wo@Wl) + bo', fused BN-stats ----------------
// block: 256 threads = 4 waves, 16 nodes; wave w computes feature tile [16w, 16w+16)
// A (16 x 832) staged in LDS as bf16, row stride 840 (16B-aligned, bank-friendly)
// B streamed from global Wtb[f][k] (bf16, L2-resident, 106 KB total)
__global__ __launch_bounds__(256) void post_kernel(const float* __restrict__ x2,
                                                   const float* __restrict__ meanI, const float* __restrict__ mnI,
                                                   const float* __restrict__ mxI, const float* __restrict__ sdI,
                                                   const float* __restrict__ cnt,
                                                   const __hip_bfloat16* __restrict__ Wtb, const float* __restrict__ boF,
                                                   float* __restrict__ out_pre,
                                                   float* __restrict__ bnsum, float* __restrict__ bnsum2) {
    __shared__ __hip_bfloat16 As[16 * 840];
    int tid = threadIdx.x, w = tid >> 6, f = tid & 63;
    int base = blockIdx.x * 16;      // 100000/16 = 6250 blocks exactly

    // phase A: build scaled feature vectors (bf16)
    for (int g = 0; g < 4; ++g) {
        int n = g * 4 + w;
        int v = base + n;
        size_t o = (size_t)v * 64 + f;
        float c = cnt[v];
        float d = fmaxf(c, 1.f);
        float mean = meanI[o];
        float sd = sdI[o];
        float mn = mnI[o];
        float mx = mxI[o];
        float amp = logf(d + 1.f) / AVG_LOG_F;
        float iamp = 1.f / amp;
        __hip_bfloat16* row = &As[n * 840];
        row[f]        = __float2bfloat16(x2[o]);
        row[64 + f]   = __float2bfloat16(mean);
        row[128 + f]  = __float2bfloat16(mn);
        row[192 + f]  = __float2bfloat16(mx);
        row[256 + f]  = __float2bfloat16(sd);
        row[320 + f]  = __float2bfloat16(mean * amp);
        row[384 + f]  = __float2bfloat16(mn * amp);
        row[448 + f]  = __float2bfloat16(mx * amp);
        row[512 + f]  = __float2bfloat16(sd * amp);
        row[576 + f]  = __float2bfloat16(mean * iamp);
        row[640 + f]  = __float2bfloat16(mn * iamp);
        row[704 + f]  = __float2bfloat16(mx * iamp);
        row[768 + f]  = __float2bfloat16(sd * iamp);
    }
    __syncthreads();

    // phase B: MFMA. lane = m + 16q; A[m][k=q*8+j], B[k=q*8+j][n=m], D: col=lane&15, row=q*4+reg
    int m = f & 15, q = f >> 4;
    int fbase = w * 16;
    f32x4 acc = {0.f, 0.f, 0.f, 0.f};
    const __hip_bfloat16* arow = &As[m * 840 + q * 8];
    const __hip_bfloat16* brow = &Wtb[(size_t)(fbase + m) * 832 + q * 8];
    #pragma unroll 2
    for (int s = 0; s < 26; ++s) {
        short8 af = *(const short8*)(arow + s * 32);
        short8 bf = *(const short8*)(brow + s * 32);
        acc = __builtin_amdgcn_mfma_f32_16x16x32_bf16(af, bf, acc, 0, 0, 0);
    }

    float bof = boF[fbase + m];
    float p1 = 0.f, p2 = 0.f;
    #pragma unroll
    for (int r = 0; r < 4; ++r) {
        float vv = acc[r] + bof;
        out_pre[(size_t)(base + q * 4 + r) * 64 + fbase + m] = vv;
        p1 += vv; p2 += vv * vv;
    }
    // reduce across the 4 quads (same feature col)
    p1 += __shfl_xor(p1, 16); p2 += __shfl_xor(p2, 16);
    p1 += __shfl_xor(p1, 32); p2 += __shfl_xor(p2, 32);
    if (f < 16) {
        atomAddF(&bnsum[fbase + f], p1);
        atomAddF(&bnsum2[fbase + f], p2);
    }
}

// ---------------- BN finalize ----------------
__global__ void bn_finalize(const float* __restrict__ bnsum, const float* __restrict__ bnsum2,
                            const float* __restrict__ gamma, const float* __restrict__ beta,
                            float* __restrict__ bnscale, float* __restrict__ bnshift) {
    int f = threadIdx.x;
    if (f < 64) {
        float mu = bnsum[f] * (1.0f / NN);
        float var = bnsum2[f] * (1.0f / NN) - mu * mu;
        float sc = gamma[f] / sqrtf(var + 1e-5f);
        bnscale[f] = sc;
        bnshift[f] = beta[f] - mu * sc;
    }
}

// ---------------- BN apply + ReLU + global_add_pool ----------------
__global__ __launch_bounds__(256) void bn_pool(const float* __restrict__ out_pre, const int* __restrict__ batch,
                                               const float* __restrict__ bnscale, const float* __restrict__ bnshift,
                                               float* __restrict__ pooled) {
    __shared__ float red[256];
    int tid = threadIdx.x, f = tid & 63, q = tid >> 6;
    int base = blockIdx.x * 64;
    float sc = bnscale[f], sh = bnshift[f];
    int b_first = batch[base < NN ? base : NN - 1];
    int last = base + 63; if (last >= NN) last = NN - 1;
    int b_last = batch[last];
    if (b_first == b_last) {
        float local = 0.f;
        for (int g = 0; g < 16; ++g) {
            int v = base + g * 4 + q;
            if (v < NN) local += fmaxf(out_pre[(size_t)v * 64 + f] * sc + sh, 0.f);
        }
        red[tid] = local;
        __syncthreads();
        if (tid < 64) atomAddF(&pooled[b_first * 64 + f], red[f] + red[f + 64] + red[f + 128] + red[f + 192]);
    } else {
        for (int g = 0; g < 16; ++g) {
            int v = base + g * 4 + q;
            if (v < NN) {
                float val = fmaxf(out_pre[(size_t)v * 64 + f] * sc + sh, 0.f);
                atomAddF(&pooled[batch[v] * 64 + f], val);
            }
        }
    }
}

// ---------------- head MLP: relu(pooled@Wm1+bm1)@Wm2+bm2 ----------------
__global__ void head_kernel(const float* __restrict__ pooled,
                            const float* __restrict__ Wm1, const float* __restrict__ bm1,
                            const float* __restrict__ Wm2, const float* __restrict__ bm2,
                            float* __restrict__ out) {
    __shared__ float ts[64][104];
    int tid = threadIdx.x;
    for (int t = tid; t < 64 * 100; t += 256) {
        int b = t / 100, j = t % 100;
        float acc = bm1[j];
        for (int k = 0; k < 64; k++) acc += pooled[b * 64 + k] * Wm1[k * 100 + j];
        ts[b][j] = fmaxf(acc, 0.f);
    }
    __syncthreads();
    if (tid < 64) {
        float acc = bm2[0];
        for (int j = 0; j < 100; j++) acc += ts[tid][j] * Wm2[j];
        out[tid] = acc;
    }
}

extern "C" void kernel_launch(void* const* d_in, const int* in_sizes, int n_in,
                              void* d_out, int out_size, void* d_ws, size_t ws_size,
                              hipStream_t stream) {
    const float* x    = (const float*)d_in[0];
    const float* ea   = (const float*)d_in[1];
    const int*   ei   = (const int*)d_in[2];
    const int*   batch= (const int*)d_in[3];
    const float* W1   = (const float*)d_in[4];
    const float* b1   = (const float*)d_in[5];
    const float* W2   = (const float*)d_in[6];
    const float* b2   = (const float*)d_in[7];
    const float* We   = (const float*)d_in[8];
    const float* be   = (const float*)d_in[9];
    const float* Wp   = (const float*)d_in[10];
    const float* bp   = (const float*)d_in[11];
    const float* Wo   = (const float*)d_in[12];
    const float* bo   = (const float*)d_in[13];
    const float* Wl   = (const float*)d_in[14];
    const float* bl   = (const float*)d_in[15];
    const float* gamma= (const float*)d_in[16];
    const float* beta = (const float*)d_in[17];
    const float* Wm1  = (const float*)d_in[18];
    const float* bm1  = (const float*)d_in[19];
    const float* Wm2  = (const float*)d_in[20];
    const float* bm2  = (const float*)d_in[21];

    float* ws = (float*)d_ws;
    constexpr size_t NF = (size_t)NN * 64;              // 6,400,000
    const size_t o_x2     = 0;
    const size_t o_B      = NF;
    const size_t o_A      = 2 * NF;                     // reused as out_pre after agg_kernel
    const size_t o_mean   = 3 * NF;
    const size_t o_mn     = 4 * NF;
    const size_t o_mx     = 5 * NF;
    const size_t o_sd     = 6 * NF;
    const size_t o_cntf   = 7 * NF;
    const size_t o_start  = o_cntf + NN;                // NN+1 uints
    const size_t o_cnt_i  = o_start + NN + 2;           // NN uints (memset 0)
    const size_t o_bsum   = o_cnt_i + NN;
    const size_t o_boff   = o_bsum + 512;
    const size_t o_perm   = o_boff + 512;               // NE uints
    const size_t o_Wtb    = o_perm + NE;                // 64*832 bf16 = 26624 float slots
    const size_t o_Wep    = o_Wtb + 64 * 832 / 2;
    const size_t o_bpF    = o_Wep + 16 * 64;
    const size_t o_boF    = o_bpF + 64;
    const size_t o_bnscale= o_boF + 64;
    const size_t o_bnshift= o_bnscale + 64;
    const size_t o_pooled = o_bnshift + 64;             // zero block: pooled + bnsum + bnsum2
    const size_t o_bnsum  = o_pooled + 64 * 64;
    const size_t o_bnsum2 = o_bnsum + 64;

    // zero the histogram and the small accumulators
    hipMemsetAsync(ws + o_cnt_i, 0, NN * sizeof(unsigned), stream);
    hipMemsetAsync(ws + o_pooled, 0, (64 * 64 + 128) * sizeof(float), stream);

    fold_weights<<<213, 256, 0, stream>>>(Wo, Wl, bo, bl, We, Wp, bp, be,
                                          (__hip_bfloat16*)(ws + o_Wtb), ws + o_Wep, ws + o_bpF, ws + o_boF);
    node_pre<<<1024, 256, 0, stream>>>(x, W1, b1, W2, b2, Wp,
                                       ws + o_x2, ws + o_A, ws + o_B);
    hist_kernel<<<6250, 256, 0, stream>>>(ei, (unsigned*)(ws + o_cnt_i));
    scan_blocksum<<<NSCAN_BLOCKS, 256, 0, stream>>>((unsigned*)(ws + o_cnt_i), (unsigned*)(ws + o_bsum));
    scan_top<<<1, 512, 0, stream>>>((unsigned*)(ws + o_bsum), (unsigned*)(ws + o_boff),
                                    (unsigned*)(ws + o_start));
    scan_final<<<NSCAN_BLOCKS, 256, 0, stream>>>((unsigned*)(ws + o_cnt_i), (unsigned*)(ws + o_boff),
                                                 (unsigned*)(ws + o_start));
    scatter_kernel<<<6250, 256, 0, stream>>>(ei, (const unsigned*)(ws + o_start),
                                             (unsigned*)(ws + o_cnt_i), (unsigned*)(ws + o_perm));
    agg_kernel<<<4096, 256, 0, stream>>>(ea, ei, (const unsigned*)(ws + o_perm),
                                         (const unsigned*)(ws + o_start),
                                         ws + o_A, ws + o_B, ws + o_Wep, ws + o_bpF,
                                         ws + o_mean, ws + o_mn, ws + o_mx, ws + o_sd, ws + o_cntf);
    post_kernel<<<6250, 256, 0, stream>>>(ws + o_x2, ws + o_mean, ws + o_mn, ws + o_mx, ws + o_sd,
                                          ws + o_cntf, (const __hip_bfloat16*)(ws + o_Wtb), ws + o_boF,
                                          ws + o_A /*out_pre*/, ws + o_bnsum, ws + o_bnsum2);
    bn_finalize<<<1, 64, 0, stream>>>(ws + o_bnsum, ws + o_bnsum2, gamma, beta,
                                      ws + o_bnscale, ws + o_bnshift);
    bn_pool<<<1563, 256, 0, stream>>>(ws + o_A /*out_pre*/, batch,
                                      ws + o_bnscale, ws + o_bnshift, ws + o_pooled);
    head_kernel<<<1, 256, 0, stream>>>(ws + o_pooled, Wm1, bm1, Wm2, bm2, (float*)d_out);
}